// Round 1
// baseline (170.197 us; speedup 1.0000x reference)
//
#include <hip/hip_runtime.h>
#include <math.h>

// Problem size: B*C*H*W = 64*1*512*512
#define N_TOTAL 16777216

// Six accumulators in d_ws (double): sx, st, sx2, st2, sxt, sbce
#define ACC_COUNT 6

__global__ __launch_bounds__(256) void loss_reduce_kernel(
    const float4* __restrict__ x4,
    const float4* __restrict__ t4,
    double* __restrict__ acc,
    int n4)
{
    float sx = 0.f, st = 0.f, sx2 = 0.f, st2 = 0.f, sxt = 0.f, sb = 0.f;

    int idx    = blockIdx.x * blockDim.x + threadIdx.x;
    int stride = gridDim.x * blockDim.x;

    for (int i = idx; i < n4; i += stride) {
        float4 xv = x4[i];
        float4 tv = t4[i];
        const float* xp = reinterpret_cast<const float*>(&xv);
        const float* tp = reinterpret_cast<const float*>(&tv);
        #pragma unroll
        for (int j = 0; j < 4; ++j) {
            float x = xp[j];
            float t = tp[j];
            sx  += x;
            st  += t;
            sx2 += x * x;
            st2 += t * t;
            sxt += x * t;
            // BCE term: t*max(log(x),-100) + (1-t)*max(log1p(-x),-100)
            float lp  = fmaxf(__logf(x), -100.0f);
            float l1p = fmaxf(__logf(1.0f - x), -100.0f);
            sb += t * lp + (1.0f - t) * l1p;
        }
    }

    // ---- wave (64-lane) reduction ----
    #pragma unroll
    for (int off = 32; off > 0; off >>= 1) {
        sx  += __shfl_down(sx,  off);
        st  += __shfl_down(st,  off);
        sx2 += __shfl_down(sx2, off);
        st2 += __shfl_down(st2, off);
        sxt += __shfl_down(sxt, off);
        sb  += __shfl_down(sb,  off);
    }

    // ---- block reduction across 4 waves ----
    __shared__ float lds[4][ACC_COUNT];
    int lane = threadIdx.x & 63;
    int wid  = threadIdx.x >> 6;
    if (lane == 0) {
        lds[wid][0] = sx;  lds[wid][1] = st;  lds[wid][2] = sx2;
        lds[wid][3] = st2; lds[wid][4] = sxt; lds[wid][5] = sb;
    }
    __syncthreads();

    if (threadIdx.x == 0) {
        double bsum[ACC_COUNT];
        #pragma unroll
        for (int k = 0; k < ACC_COUNT; ++k) {
            float v = lds[0][k] + lds[1][k] + lds[2][k] + lds[3][k];
            bsum[k] = (double)v;
        }
        #pragma unroll
        for (int k = 0; k < ACC_COUNT; ++k) {
            atomicAdd(&acc[k], bsum[k]);
        }
    }
}

__global__ void loss_finalize_kernel(const double* __restrict__ acc,
                                     float* __restrict__ out)
{
    double sx  = acc[0];
    double st  = acc[1];
    double sx2 = acc[2];
    double st2 = acc[3];
    double sxt = acc[4];
    double sb  = acc[5];

    const double n = (double)N_TOTAL;

    // BCE
    double bce = -sb / n;

    // NCC (stop_gradient irrelevant for forward value)
    double xm = sx / n;
    double tm = st / n;
    double xs = sqrt((sx2 - sx * sx / n) / (n - 1.0)); // unbiased std
    double ts = sqrt((st2 - st * st / n) / (n - 1.0));
    double ncc = (sxt - n * xm * tm) / (xs * ts * n);

    // Tversky
    const double beta = 0.1, adding = 1.0;
    double TP = sxt;
    double FP = sx - sxt;
    double FN = st - sxt;
    double tversky = (TP + adding) / (TP + beta * FP + (1.0 - beta) * FN + adding);

    const double alpha = 0.5;
    double res = (1.0 - (alpha * ncc + (1.0 - alpha) * tversky)) * bce;

    out[0] = (float)res;
}

extern "C" void kernel_launch(void* const* d_in, const int* in_sizes, int n_in,
                              void* d_out, int out_size, void* d_ws, size_t ws_size,
                              hipStream_t stream)
{
    const float* x = (const float*)d_in[0];
    const float* t = (const float*)d_in[1];
    float* out = (float*)d_out;
    double* acc = (double*)d_ws;

    int n  = in_sizes[0];
    int n4 = n / 4;

    // d_ws is NOT re-poisoned between replays — zero accumulators every call.
    hipMemsetAsync(acc, 0, ACC_COUNT * sizeof(double), stream);

    const int block = 256;
    int grid = (n4 + block - 1) / block;
    if (grid > 2048) grid = 2048;

    loss_reduce_kernel<<<grid, block, 0, stream>>>(
        (const float4*)x, (const float4*)t, acc, n4);
    loss_finalize_kernel<<<1, 1, 0, stream>>>(acc, out);
}

// Round 2
// 33.236 us; speedup vs baseline: 5.1209x; 5.1209x over previous
//
#include <hip/hip_runtime.h>
#include <math.h>

// Problem size: B*C*H*W = 64*1*512*512
#define N_TOTAL 16777216
#define ACC_COUNT 6     // sx, st, sx2, st2, sxt, sbce
#define MAX_BLOCKS 2048

__global__ __launch_bounds__(256) void loss_reduce_kernel(
    const float4* __restrict__ x4,
    const float4* __restrict__ t4,
    float* __restrict__ partials,   // [gridDim.x][ACC_COUNT]
    int n4)
{
    float sx = 0.f, st = 0.f, sx2 = 0.f, st2 = 0.f, sxt = 0.f, sb = 0.f;

    int idx    = blockIdx.x * blockDim.x + threadIdx.x;
    int stride = gridDim.x * blockDim.x;

    for (int i = idx; i < n4; i += stride) {
        float4 xv = x4[i];
        float4 tv = t4[i];
        const float* xp = reinterpret_cast<const float*>(&xv);
        const float* tp = reinterpret_cast<const float*>(&tv);
        #pragma unroll
        for (int j = 0; j < 4; ++j) {
            float x = xp[j];
            float t = tp[j];
            sx  += x;
            st  += t;
            sx2 += x * x;
            st2 += t * t;
            sxt += x * t;
            // BCE term: t*max(log(x),-100) + (1-t)*max(log1p(-x),-100)
            float lp  = fmaxf(__logf(x), -100.0f);
            float l1p = fmaxf(__logf(1.0f - x), -100.0f);
            sb += t * lp + (1.0f - t) * l1p;
        }
    }

    // ---- wave (64-lane) reduction ----
    #pragma unroll
    for (int off = 32; off > 0; off >>= 1) {
        sx  += __shfl_down(sx,  off);
        st  += __shfl_down(st,  off);
        sx2 += __shfl_down(sx2, off);
        st2 += __shfl_down(st2, off);
        sxt += __shfl_down(sxt, off);
        sb  += __shfl_down(sb,  off);
    }

    // ---- block reduction across 4 waves, then ONE store per block ----
    __shared__ float lds[4][ACC_COUNT];
    int lane = threadIdx.x & 63;
    int wid  = threadIdx.x >> 6;
    if (lane == 0) {
        lds[wid][0] = sx;  lds[wid][1] = st;  lds[wid][2] = sx2;
        lds[wid][3] = st2; lds[wid][4] = sxt; lds[wid][5] = sb;
    }
    __syncthreads();

    if (threadIdx.x < ACC_COUNT) {
        int k = threadIdx.x;
        float v = lds[0][k] + lds[1][k] + lds[2][k] + lds[3][k];
        partials[blockIdx.x * ACC_COUNT + k] = v;   // plain store, no atomics
    }
}

__global__ __launch_bounds__(256) void loss_finalize_kernel(
    const float* __restrict__ partials,
    float* __restrict__ out,
    int nblocks)
{
    double a[ACC_COUNT] = {0, 0, 0, 0, 0, 0};

    for (int r = threadIdx.x; r < nblocks; r += blockDim.x) {
        #pragma unroll
        for (int k = 0; k < ACC_COUNT; ++k)
            a[k] += (double)partials[r * ACC_COUNT + k];
    }

    // wave reduction (doubles)
    #pragma unroll
    for (int off = 32; off > 0; off >>= 1) {
        #pragma unroll
        for (int k = 0; k < ACC_COUNT; ++k)
            a[k] += __shfl_down(a[k], off);
    }

    __shared__ double lds[4][ACC_COUNT];
    int lane = threadIdx.x & 63;
    int wid  = threadIdx.x >> 6;
    if (lane == 0) {
        #pragma unroll
        for (int k = 0; k < ACC_COUNT; ++k) lds[wid][k] = a[k];
    }
    __syncthreads();

    if (threadIdx.x == 0) {
        double sx  = lds[0][0] + lds[1][0] + lds[2][0] + lds[3][0];
        double st  = lds[0][1] + lds[1][1] + lds[2][1] + lds[3][1];
        double sx2 = lds[0][2] + lds[1][2] + lds[2][2] + lds[3][2];
        double st2 = lds[0][3] + lds[1][3] + lds[2][3] + lds[3][3];
        double sxt = lds[0][4] + lds[1][4] + lds[2][4] + lds[3][4];
        double sb  = lds[0][5] + lds[1][5] + lds[2][5] + lds[3][5];

        const double n = (double)N_TOTAL;

        // BCE
        double bce = -sb / n;

        // NCC
        double xm = sx / n;
        double tm = st / n;
        double xs = sqrt((sx2 - sx * sx / n) / (n - 1.0)); // unbiased std
        double ts = sqrt((st2 - st * st / n) / (n - 1.0));
        double ncc = (sxt - n * xm * tm) / (xs * ts * n);

        // Tversky
        const double beta = 0.1, adding = 1.0;
        double TP = sxt;
        double FP = sx - sxt;
        double FN = st - sxt;
        double tversky = (TP + adding) / (TP + beta * FP + (1.0 - beta) * FN + adding);

        const double alpha = 0.5;
        double res = (1.0 - (alpha * ncc + (1.0 - alpha) * tversky)) * bce;

        out[0] = (float)res;
    }
}

extern "C" void kernel_launch(void* const* d_in, const int* in_sizes, int n_in,
                              void* d_out, int out_size, void* d_ws, size_t ws_size,
                              hipStream_t stream)
{
    const float* x = (const float*)d_in[0];
    const float* t = (const float*)d_in[1];
    float* out = (float*)d_out;
    float* partials = (float*)d_ws;

    int n  = in_sizes[0];
    int n4 = n / 4;

    const int block = 256;
    int grid = (n4 + block - 1) / block;
    if (grid > MAX_BLOCKS) grid = MAX_BLOCKS;

    loss_reduce_kernel<<<grid, block, 0, stream>>>(
        (const float4*)x, (const float4*)t, partials, n4);
    loss_finalize_kernel<<<1, block, 0, stream>>>(partials, out, grid);
}